// Round 4
// baseline (156.442 us; speedup 1.0000x reference)
//
#include <hip/hip_runtime.h>

#define EPSF 1e-20f

__device__ __forceinline__ float frcp(float x) { return __builtin_amdgcn_rcpf(x); }

// ===========================================================================
// Pipeline runs in (U, c) representation, U = x*c.
//   nconv: den = conv(c); nom = conv(U); x = nom/(den+eps)+b; c' = den/sum(w);
//          U' = x*c'.
//   maxpool (argmax over c, torch first-max): U' = U_sel/4, c' = c_max/4.
//   up2: replicate (fused as half-res reads).
//   final 1x1: out = (w0*U0+w1*U1)/(w0*c0+w1*c1+eps)+b ; cout = den/(w0+w1).
// ===========================================================================

// ---------------------------------------------------------------------------
// Conv core on LDS tiles, row stride 72, window 12 floats at lw.
// ---------------------------------------------------------------------------
template<int NCI, int CI0, int CINT, int K, int ROWS>
__device__ __forceinline__ void conv_core(const float* __restrict__ s_d,
                                          const float* __restrict__ s_c,
                                          const float* __restrict__ wgt,
                                          int lh, int lw,
                                          float den[2][4], float nom[2][4])
{
    constexpr int JOFF = 4 - (K / 2);
    #pragma unroll
    for (int kh = 0; kh < K; ++kh) {
        #pragma unroll
        for (int ci = 0; ci < NCI; ++ci) {
            const float4* rd = (const float4*)(s_d + (ci * ROWS + lh + kh) * 72 + lw);
            const float4* rc = (const float4*)(s_c + (ci * ROWS + lh + kh) * 72 + lw);
            float wd[12], wc[12];
            #pragma unroll
            for (int q = 0; q < 3; ++q) {
                const float4 t = rd[q];
                wd[4*q] = t.x; wd[4*q+1] = t.y; wd[4*q+2] = t.z; wd[4*q+3] = t.w;
                const float4 u = rc[q];
                wc[4*q] = u.x; wc[4*q+1] = u.y; wc[4*q+2] = u.z; wc[4*q+3] = u.w;
            }
            #pragma unroll
            for (int kw = 0; kw < K; ++kw) {
                const float w0 = wgt[((0 * CINT + CI0 + ci) * K + kh) * K + kw];
                const float w1 = wgt[((1 * CINT + CI0 + ci) * K + kh) * K + kw];
                #pragma unroll
                for (int p = 0; p < 4; ++p) {
                    const int j = p + kw + JOFF;
                    den[0][p] = fmaf(w0, wc[j], den[0][p]);
                    nom[0][p] = fmaf(w0, wd[j], nom[0][p]);
                    den[1][p] = fmaf(w1, wc[j], den[1][p]);
                    nom[1][p] = fmaf(w1, wd[j], nom[1][p]);
                }
            }
        }
    }
}

// ---------------------------------------------------------------------------
// Conv over half-res (2x-replicated) LDS tiles [2][10][40]; K=3 only.
// Low tile origin: row (base_h/2 - 1), col (base_w/2 - 4).
// ---------------------------------------------------------------------------
template<int LO0>
__device__ __forceinline__ void conv_low(const float* __restrict__ s_lo_d,
                                         const float* __restrict__ s_lo_c,
                                         const float* __restrict__ wgt,
                                         int lh, int lw,
                                         float den[2][4], float nom[2][4])
{
    #pragma unroll
    for (int kh = 0; kh < 3; ++kh) {
        const int rel_r = ((lh + kh - 1) >> 1) + 1;
        #pragma unroll
        for (int lci = 0; lci < 2; ++lci) {
            const float* rd = s_lo_d + (lci * 10 + rel_r) * 40 + (lw >> 1) + 2;
            const float* rc = s_lo_c + (lci * 10 + rel_r) * 40 + (lw >> 1) + 2;
            float wd[6], wc[6];
            #pragma unroll
            for (int q = 0; q < 3; ++q) {
                const float2 t = *(const float2*)(rd + 2 * q);
                wd[2*q] = t.x; wd[2*q+1] = t.y;
                const float2 u = *(const float2*)(rc + 2 * q);
                wc[2*q] = u.x; wc[2*q+1] = u.y;
            }
            #pragma unroll
            for (int kw = 0; kw < 3; ++kw) {
                const float w0 = wgt[((0 * 4 + LO0 + lci) * 3 + kh) * 3 + kw];
                const float w1 = wgt[((1 * 4 + LO0 + lci) * 3 + kh) * 3 + kw];
                #pragma unroll
                for (int p = 0; p < 4; ++p) {
                    const int t = p + kw - 1;
                    const int jl = ((t < 0) ? -1 : (t >> 1)) + 2;
                    den[0][p] = fmaf(w0, wc[jl], den[0][p]);
                    nom[0][p] = fmaf(w0, wd[jl], nom[0][p]);
                    den[1][p] = fmaf(w1, wc[jl], den[1][p]);
                    nom[1][p] = fmaf(w1, wd[jl], nom[1][p]);
                }
            }
        }
    }
}

template<int CINT, int K>
__device__ __forceinline__ void nconv_epilogue(const float* __restrict__ wgt,
                                               const float* __restrict__ bias,
                                               float den[2][4], float nom[2][4],
                                               float4 uo[2], float4 co4[2])
{
    #pragma unroll
    for (int c = 0; c < 2; ++c) {
        float s = 0.f;
        for (int i = 0; i < CINT * K * K; ++i) s += wgt[c * CINT * K * K + i];
        const float is = 1.0f / s;
        const float bb = bias[c];
        #pragma unroll
        for (int p = 0; p < 4; ++p) {
            const float xo = nom[c][p] * frcp(den[c][p] + EPSF) + bb;
            const float cv = den[c][p] * is;
            (&co4[c].x)[p] = cv;
            (&uo[c].x)[p]  = xo * cv;
        }
    }
}

// ---------------------------------------------------------------------------
// Single tiled nconv (used for enc stage 3 @512 with fused pool).
// ---------------------------------------------------------------------------
template<int CIN, int K, int LOGHW, bool IN_IS_U, bool POOL>
__global__ __launch_bounds__(256)
void nconv_tiled(const float* __restrict__ xin, const float* __restrict__ cin_,
                 const float* __restrict__ wgt, const float* __restrict__ bias,
                 float* __restrict__ uout, float* __restrict__ cout,
                 float* __restrict__ poolU, float* __restrict__ poolC)
{
    constexpr int HW = 1 << LOGHW;
    constexpr int PAD = K / 2;
    constexpr int TH = 16;
    constexpr int ROWS = TH + 2 * PAD;
    constexpr int NC4 = 18;
    __shared__ __align__(16) float s_d[CIN][ROWS][72];
    __shared__ __align__(16) float s_c[CIN][ROWS][72];

    const int tid = threadIdx.x;
    const int base_w = blockIdx.x * 64;
    const int base_h = blockIdx.y * TH;
    const int b = blockIdx.z;

    constexpr int SLOTS = CIN * ROWS * NC4;
    const float4* x4 = (const float4*)xin;
    const float4* c4p = (const float4*)cin_;
    for (int i = tid; i < SLOTS; i += 256) {
        const int ci = i / (ROWS * NC4);
        const int r  = (i / NC4) % ROWS;
        const int cf = i % NC4;
        const int gh = base_h - PAD + r;
        const int gw4 = (base_w >> 2) + cf - 1;
        float4 dd = make_float4(0.f, 0.f, 0.f, 0.f);
        float4 cc = make_float4(0.f, 0.f, 0.f, 0.f);
        if ((unsigned)gh < (unsigned)HW && (unsigned)gw4 < (unsigned)(HW >> 2)) {
            const int a = ((b * CIN + ci) << (2 * LOGHW - 2)) + (gh << (LOGHW - 2)) + gw4;
            const float4 xx = x4[a];
            cc = c4p[a];
            if (IN_IS_U) dd = xx;
            else dd = make_float4(xx.x * cc.x, xx.y * cc.y, xx.z * cc.z, xx.w * cc.w);
        }
        *(float4*)&s_d[ci][r][cf * 4] = dd;
        *(float4*)&s_c[ci][r][cf * 4] = cc;
    }
    __syncthreads();

    const int lh = tid >> 4;
    const int lw = (tid & 15) << 2;
    float den[2][4], nom[2][4];
    #pragma unroll
    for (int c = 0; c < 2; ++c)
        #pragma unroll
        for (int p = 0; p < 4; ++p) { den[c][p] = 0.f; nom[c][p] = 0.f; }

    conv_core<CIN, 0, CIN, K, ROWS>(&s_d[0][0][0], &s_c[0][0][0], wgt, lh, lw, den, nom);

    float4 uo[2], co4[2];
    nconv_epilogue<CIN, K>(wgt, bias, den, nom, uo, co4);

    const int oh = base_h + lh;
    #pragma unroll
    for (int c = 0; c < 2; ++c) {
        const int a = ((b * 2 + c) << (2 * LOGHW - 2)) + (oh << (LOGHW - 2)) + ((base_w + lw) >> 2);
        ((float4*)uout)[a] = uo[c];
        ((float4*)cout)[a] = co4[c];
    }

    if (POOL) {
        __syncthreads();
        float* pu = &s_d[0][0][0];
        float* pcb = &s_c[0][0][0];
        #pragma unroll
        for (int c = 0; c < 2; ++c) {
            *(float4*)&pu[(c * 16 + lh) * 64 + lw] = uo[c];
            *(float4*)&pcb[(c * 16 + lh) * 64 + lw] = co4[c];
        }
        __syncthreads();
        #pragma unroll
        for (int rep = 0; rep < 2; ++rep) {
            const int o = tid + rep * 256;
            const int ch = o >> 8;
            const int idx = o & 255;
            const int pr = idx >> 5;
            const int pcc = idx & 31;
            const int bse = (ch * 16 + 2 * pr) * 64 + 2 * pcc;
            const float c00 = pcb[bse],      c01 = pcb[bse + 1];
            const float c10 = pcb[bse + 64], c11 = pcb[bse + 65];
            float m = c00; float g = pu[bse];
            if (c01 > m) { m = c01; g = pu[bse + 1]; }
            if (c10 > m) { m = c10; g = pu[bse + 64]; }
            if (c11 > m) { m = c11; g = pu[bse + 65]; }
            const int pa = ((b * 2 + ch) << (2 * (LOGHW - 1)))
                         + (((base_h >> 1) + pr) << (LOGHW - 1)) + (base_w >> 1) + pcc;
            poolU[pa] = g * 0.25f;
            poolC[pa] = m * 0.25f;
        }
    }
}

// ---------------------------------------------------------------------------
// Fused double nconv (5x5 then 5x5). Stage A computed on padded 72x20 region
// into LDS (OOB-masked to zero = exact zero-pad semantics), stage B consumes.
// Optional fused 2x2 pool of stage-B output.
// ---------------------------------------------------------------------------
template<int CIN, int LOGHW, bool IN_IS_U, bool POOL>
__global__ __launch_bounds__(256)
void nconv2_tiled(const float* __restrict__ xin, const float* __restrict__ cin_,
                  const float* __restrict__ wA, const float* __restrict__ bA,
                  const float* __restrict__ wB, const float* __restrict__ bB,
                  float* __restrict__ uout, float* __restrict__ cout,
                  float* __restrict__ poolU, float* __restrict__ poolC)
{
    constexpr int HW = 1 << LOGHW;
    __shared__ __align__(16) float s_in_d[CIN][28][80];
    __shared__ __align__(16) float s_in_c[CIN][28][80];
    __shared__ __align__(16) float s_mid_d[2][20][72];
    __shared__ __align__(16) float s_mid_c[2][20][72];

    const int tid = threadIdx.x;
    const int base_w = blockIdx.x * 64;
    const int base_h = blockIdx.y * 16;
    const int b = blockIdx.z;

    // Stage input: rows [bh-6, bh+22), cols [bw-8, bw+72)
    constexpr int SLOTS = CIN * 28 * 20;
    const float4* x4 = (const float4*)xin;
    const float4* c4p = (const float4*)cin_;
    for (int i = tid; i < SLOTS; i += 256) {
        const int ci = i / (28 * 20);
        const int r  = (i / 20) % 28;
        const int cf = i % 20;
        const int gh = base_h - 6 + r;
        const int gw4 = (base_w >> 2) - 2 + cf;
        float4 dd = make_float4(0.f, 0.f, 0.f, 0.f);
        float4 cc = make_float4(0.f, 0.f, 0.f, 0.f);
        if ((unsigned)gh < (unsigned)HW && (unsigned)gw4 < (unsigned)(HW >> 2)) {
            const int a = ((b * CIN + ci) << (2 * LOGHW - 2)) + (gh << (LOGHW - 2)) + gw4;
            const float4 xx = x4[a];
            cc = c4p[a];
            if (IN_IS_U) dd = xx;
            else dd = make_float4(xx.x * cc.x, xx.y * cc.y, xx.z * cc.z, xx.w * cc.w);
        }
        *(float4*)&s_in_d[ci][r][cf * 4] = dd;
        *(float4*)&s_in_c[ci][r][cf * 4] = cc;
    }
    __syncthreads();

    // Stage A: intermediate on rows [bh-2, bh+18) x cols [bw-4, bw+68)
    {
        float sA[2];
        #pragma unroll
        for (int c = 0; c < 2; ++c) {
            float s = 0.f;
            for (int i = 0; i < CIN * 25; ++i) s += wA[c * CIN * 25 + i];
            sA[c] = 1.0f / s;
        }
        for (int s = tid; s < 360; s += 256) {
            const int r = s / 18;
            const int g = s % 18;
            float den[2][4], nom[2][4];
            #pragma unroll
            for (int c = 0; c < 2; ++c)
                #pragma unroll
                for (int p = 0; p < 4; ++p) { den[c][p] = 0.f; nom[c][p] = 0.f; }
            #pragma unroll
            for (int kh = 0; kh < 5; ++kh) {
                #pragma unroll
                for (int ci = 0; ci < CIN; ++ci) {
                    const float4* rd = (const float4*)(&s_in_d[ci][r + kh + 2][4 * g]);
                    const float4* rc = (const float4*)(&s_in_c[ci][r + kh + 2][4 * g]);
                    float wd[12], wc[12];
                    #pragma unroll
                    for (int q = 0; q < 3; ++q) {
                        const float4 t = rd[q];
                        wd[4*q] = t.x; wd[4*q+1] = t.y; wd[4*q+2] = t.z; wd[4*q+3] = t.w;
                        const float4 u = rc[q];
                        wc[4*q] = u.x; wc[4*q+1] = u.y; wc[4*q+2] = u.z; wc[4*q+3] = u.w;
                    }
                    #pragma unroll
                    for (int kw = 0; kw < 5; ++kw) {
                        const float w0 = wA[((0 * CIN + ci) * 5 + kh) * 5 + kw];
                        const float w1 = wA[((1 * CIN + ci) * 5 + kh) * 5 + kw];
                        #pragma unroll
                        for (int p = 0; p < 4; ++p) {
                            const int j = p + kw + 2;
                            den[0][p] = fmaf(w0, wc[j], den[0][p]);
                            nom[0][p] = fmaf(w0, wd[j], nom[0][p]);
                            den[1][p] = fmaf(w1, wc[j], den[1][p]);
                            nom[1][p] = fmaf(w1, wd[j], nom[1][p]);
                        }
                    }
                }
            }
            const int orow = base_h - 2 + r;
            const bool rok = (unsigned)orow < (unsigned)HW;
            #pragma unroll
            for (int c = 0; c < 2; ++c) {
                float4 du, dc;
                #pragma unroll
                for (int p = 0; p < 4; ++p) {
                    const int ocol = base_w - 4 + 4 * g + p;
                    const bool ok = rok && (unsigned)ocol < (unsigned)HW;
                    const float xo = nom[c][p] * frcp(den[c][p] + EPSF) + bA[c];
                    const float cv = den[c][p] * sA[c];
                    (&dc.x)[p] = ok ? cv : 0.f;
                    (&du.x)[p] = ok ? xo * cv : 0.f;
                }
                *(float4*)&s_mid_d[c][r][4 * g] = du;
                *(float4*)&s_mid_c[c][r][4 * g] = dc;
            }
        }
    }
    __syncthreads();

    // Stage B
    const int lh = tid >> 4;
    const int lw = (tid & 15) << 2;
    float den[2][4], nom[2][4];
    #pragma unroll
    for (int c = 0; c < 2; ++c)
        #pragma unroll
        for (int p = 0; p < 4; ++p) { den[c][p] = 0.f; nom[c][p] = 0.f; }

    conv_core<2, 0, 2, 5, 20>(&s_mid_d[0][0][0], &s_mid_c[0][0][0], wB, lh, lw, den, nom);

    float4 uo[2], co4[2];
    nconv_epilogue<2, 5>(wB, bB, den, nom, uo, co4);

    const int oh = base_h + lh;
    #pragma unroll
    for (int c = 0; c < 2; ++c) {
        const int a = ((b * 2 + c) << (2 * LOGHW - 2)) + (oh << (LOGHW - 2)) + ((base_w + lw) >> 2);
        ((float4*)uout)[a] = uo[c];
        ((float4*)cout)[a] = co4[c];
    }

    if (POOL) {
        __syncthreads();
        float* pu = &s_mid_d[0][0][0];
        float* pcb = &s_mid_c[0][0][0];
        #pragma unroll
        for (int c = 0; c < 2; ++c) {
            *(float4*)&pu[(c * 16 + lh) * 64 + lw] = uo[c];
            *(float4*)&pcb[(c * 16 + lh) * 64 + lw] = co4[c];
        }
        __syncthreads();
        #pragma unroll
        for (int rep = 0; rep < 2; ++rep) {
            const int o = tid + rep * 256;
            const int ch = o >> 8;
            const int idx = o & 255;
            const int pr = idx >> 5;
            const int pcc = idx & 31;
            const int bse = (ch * 16 + 2 * pr) * 64 + 2 * pcc;
            const float c00 = pcb[bse],      c01 = pcb[bse + 1];
            const float c10 = pcb[bse + 64], c11 = pcb[bse + 65];
            float m = c00; float g = pu[bse];
            if (c01 > m) { m = c01; g = pu[bse + 1]; }
            if (c10 > m) { m = c10; g = pu[bse + 64]; }
            if (c11 > m) { m = c11; g = pu[bse + 65]; }
            const int pa = ((b * 2 + ch) << (2 * (LOGHW - 1)))
                         + (((base_h >> 1) + pr) << (LOGHW - 1)) + (base_w >> 1) + pcc;
            poolU[pa] = g * 0.25f;
            poolC[pa] = m * 0.25f;
        }
    }
}

// ---------------------------------------------------------------------------
// Mid kernel: per 64x16 tile @128 computes the whole lower U-net:
//   x3 = nconv(p2,w2) @128 (haloed region, in LDS)
//   p3 = pool(x3) (LDS), x4 = nconv(p3,w2) @64 (LDS)
//   x34 = nconv(cat(x3, up2(x4)), w4) @128 -> global.
// ---------------------------------------------------------------------------
__global__ __launch_bounds__(256)
void mid_kern(const float* __restrict__ p2U, const float* __restrict__ p2C,
              const float* __restrict__ w2, const float* __restrict__ b2,
              const float* __restrict__ w4, const float* __restrict__ b4,
              float* __restrict__ x34U, float* __restrict__ x34C)
{
    __shared__ __align__(16) float sp_d[2][32][88], sp_c[2][32][88];
    __shared__ __align__(16) float sx3_d[2][28][80], sx3_c[2][28][80];
    __shared__ __align__(16) float sp3_d[2][14][48], sp3_c[2][14][48];
    __shared__ __align__(16) float sx4_d[2][10][40], sx4_c[2][10][40];

    const int tid = threadIdx.x;
    const int bw = blockIdx.x * 64;
    const int bh = blockIdx.y * 16;
    const int b = blockIdx.z;

    // P1: stage p2, rows [bh-8, bh+24), cols [bw-12, bw+76)
    const float4* U4 = (const float4*)p2U;
    const float4* C4 = (const float4*)p2C;
    for (int i = tid; i < 2 * 32 * 22; i += 256) {
        const int ci = i / 704;
        const int r  = (i / 22) % 32;
        const int cf = i % 22;
        const int gh = bh - 8 + r;
        const int gw4 = (bw >> 2) - 3 + cf;
        float4 dd = make_float4(0.f, 0.f, 0.f, 0.f);
        float4 cc = make_float4(0.f, 0.f, 0.f, 0.f);
        if ((unsigned)gh < 128u && (unsigned)gw4 < 32u) {
            const int a = ((b * 2 + ci) << 12) + (gh << 5) + gw4;
            dd = U4[a];
            cc = C4[a];
        }
        *(float4*)&sp_d[ci][r][cf * 4] = dd;
        *(float4*)&sp_c[ci][r][cf * 4] = cc;
    }
    __syncthreads();

    // P2: x3 on rows [bh-6, bh+22) x cols [bw-8, bw+72)
    {
        float s2[2];
        #pragma unroll
        for (int c = 0; c < 2; ++c) {
            float s = 0.f;
            for (int i = 0; i < 50; ++i) s += w2[c * 50 + i];
            s2[c] = 1.0f / s;
        }
        for (int s = tid; s < 560; s += 256) {
            const int r = s / 20;
            const int g = s % 20;
            float den[2][4], nom[2][4];
            #pragma unroll
            for (int c = 0; c < 2; ++c)
                #pragma unroll
                for (int p = 0; p < 4; ++p) { den[c][p] = 0.f; nom[c][p] = 0.f; }
            #pragma unroll
            for (int kh = 0; kh < 5; ++kh) {
                #pragma unroll
                for (int ci = 0; ci < 2; ++ci) {
                    const float4* rd = (const float4*)(&sp_d[ci][r + kh][4 * g]);
                    const float4* rc = (const float4*)(&sp_c[ci][r + kh][4 * g]);
                    float wd[12], wc[12];
                    #pragma unroll
                    for (int q = 0; q < 3; ++q) {
                        const float4 t = rd[q];
                        wd[4*q] = t.x; wd[4*q+1] = t.y; wd[4*q+2] = t.z; wd[4*q+3] = t.w;
                        const float4 u = rc[q];
                        wc[4*q] = u.x; wc[4*q+1] = u.y; wc[4*q+2] = u.z; wc[4*q+3] = u.w;
                    }
                    #pragma unroll
                    for (int kw = 0; kw < 5; ++kw) {
                        const float w0 = w2[((0 * 2 + ci) * 5 + kh) * 5 + kw];
                        const float w1 = w2[((1 * 2 + ci) * 5 + kh) * 5 + kw];
                        #pragma unroll
                        for (int p = 0; p < 4; ++p) {
                            const int j = p + kw + 2;
                            den[0][p] = fmaf(w0, wc[j], den[0][p]);
                            nom[0][p] = fmaf(w0, wd[j], nom[0][p]);
                            den[1][p] = fmaf(w1, wc[j], den[1][p]);
                            nom[1][p] = fmaf(w1, wd[j], nom[1][p]);
                        }
                    }
                }
            }
            const int orow = bh - 6 + r;
            const bool rok = (unsigned)orow < 128u;
            #pragma unroll
            for (int c = 0; c < 2; ++c) {
                float4 du, dc;
                #pragma unroll
                for (int p = 0; p < 4; ++p) {
                    const int ocol = bw - 8 + 4 * g + p;
                    const bool ok = rok && (unsigned)ocol < 128u;
                    const float xo = nom[c][p] * frcp(den[c][p] + EPSF) + b2[c];
                    const float cv = den[c][p] * s2[c];
                    (&dc.x)[p] = ok ? cv : 0.f;
                    (&du.x)[p] = ok ? xo * cv : 0.f;
                }
                *(float4*)&sx3_d[c][r][4 * g] = du;
                *(float4*)&sx3_c[c][r][4 * g] = dc;
            }
        }
    }
    __syncthreads();

    // P3: pool x3 -> p3, rows [bh/2-3, bh/2+11) x cols [bw/2-8, bw/2+40)
    for (int i = tid; i < 2 * 14 * 48; i += 256) {
        const int ch = i / 672;
        const int r  = (i / 48) % 14;
        const int c  = i % 48;
        const int R = (bh >> 1) - 3 + r;
        const int C = (bw >> 1) - 8 + c;
        float g = 0.f, m = 0.f;
        if (c >= 4 && c < 44 && (unsigned)R < 64u && (unsigned)C < 64u) {
            const int xr = 2 * r, xc = 2 * c - 8;
            const float c00 = sx3_c[ch][xr][xc],     c01 = sx3_c[ch][xr][xc + 1];
            const float c10 = sx3_c[ch][xr + 1][xc], c11 = sx3_c[ch][xr + 1][xc + 1];
            m = c00; g = sx3_d[ch][xr][xc];
            if (c01 > m) { m = c01; g = sx3_d[ch][xr][xc + 1]; }
            if (c10 > m) { m = c10; g = sx3_d[ch][xr + 1][xc]; }
            if (c11 > m) { m = c11; g = sx3_d[ch][xr + 1][xc + 1]; }
            g *= 0.25f; m *= 0.25f;
        }
        sp3_d[ch][r][c] = g;
        sp3_c[ch][r][c] = m;
    }
    __syncthreads();

    // P4: x4 = nconv5x5(p3) on rows [bh/2-1, bh/2+9) x cols [bw/2-4, bw/2+36)
    {
        float s2[2];
        #pragma unroll
        for (int c = 0; c < 2; ++c) {
            float s = 0.f;
            for (int i = 0; i < 50; ++i) s += w2[c * 50 + i];
            s2[c] = 1.0f / s;
        }
        for (int s = tid; s < 100; s += 256) {
            const int r = s / 10;
            const int g = s % 10;
            float den[2][4], nom[2][4];
            #pragma unroll
            for (int c = 0; c < 2; ++c)
                #pragma unroll
                for (int p = 0; p < 4; ++p) { den[c][p] = 0.f; nom[c][p] = 0.f; }
            #pragma unroll
            for (int kh = 0; kh < 5; ++kh) {
                #pragma unroll
                for (int ci = 0; ci < 2; ++ci) {
                    const float4* rd = (const float4*)(&sp3_d[ci][r + kh][4 * g]);
                    const float4* rc = (const float4*)(&sp3_c[ci][r + kh][4 * g]);
                    float wd[12], wc[12];
                    #pragma unroll
                    for (int q = 0; q < 3; ++q) {
                        const float4 t = rd[q];
                        wd[4*q] = t.x; wd[4*q+1] = t.y; wd[4*q+2] = t.z; wd[4*q+3] = t.w;
                        const float4 u = rc[q];
                        wc[4*q] = u.x; wc[4*q+1] = u.y; wc[4*q+2] = u.z; wc[4*q+3] = u.w;
                    }
                    #pragma unroll
                    for (int kw = 0; kw < 5; ++kw) {
                        const float w0 = w2[((0 * 2 + ci) * 5 + kh) * 5 + kw];
                        const float w1 = w2[((1 * 2 + ci) * 5 + kh) * 5 + kw];
                        #pragma unroll
                        for (int p = 0; p < 4; ++p) {
                            const int j = p + kw + 2;
                            den[0][p] = fmaf(w0, wc[j], den[0][p]);
                            nom[0][p] = fmaf(w0, wd[j], nom[0][p]);
                            den[1][p] = fmaf(w1, wc[j], den[1][p]);
                            nom[1][p] = fmaf(w1, wd[j], nom[1][p]);
                        }
                    }
                }
            }
            const int orow = (bh >> 1) - 1 + r;
            const bool rok = (unsigned)orow < 64u;
            #pragma unroll
            for (int c = 0; c < 2; ++c) {
                float4 du, dc;
                #pragma unroll
                for (int p = 0; p < 4; ++p) {
                    const int ocol = (bw >> 1) - 4 + 4 * g + p;
                    const bool ok = rok && (unsigned)ocol < 64u;
                    const float xo = nom[c][p] * frcp(den[c][p] + EPSF) + b2[c];
                    const float cv = den[c][p] * s2[c];
                    (&dc.x)[p] = ok ? cv : 0.f;
                    (&du.x)[p] = ok ? xo * cv : 0.f;
                }
                *(float4*)&sx4_d[c][r][4 * g] = du;
                *(float4*)&sx4_c[c][r][4 * g] = dc;
            }
        }
    }
    __syncthreads();

    // P5: x34 = cat-conv(x3 skip [w4 ch 0,1], up2(x4) [w4 ch 2,3]) @128
    {
        const int lh = tid >> 4;
        const int lw = (tid & 15) << 2;
        float den[2][4], nom[2][4];
        #pragma unroll
        for (int c = 0; c < 2; ++c)
            #pragma unroll
            for (int p = 0; p < 4; ++p) { den[c][p] = 0.f; nom[c][p] = 0.f; }

        // skip conv over sx3 (row0 = bh-6, col0 = bw-8): row lh+kh+5, window base lw+4
        #pragma unroll
        for (int kh = 0; kh < 3; ++kh) {
            #pragma unroll
            for (int ci = 0; ci < 2; ++ci) {
                const float4* rd = (const float4*)(&sx3_d[ci][lh + kh + 5][lw + 4]);
                const float4* rc = (const float4*)(&sx3_c[ci][lh + kh + 5][lw + 4]);
                float wd[12], wc[12];
                #pragma unroll
                for (int q = 0; q < 3; ++q) {
                    const float4 t = rd[q];
                    wd[4*q] = t.x; wd[4*q+1] = t.y; wd[4*q+2] = t.z; wd[4*q+3] = t.w;
                    const float4 u = rc[q];
                    wc[4*q] = u.x; wc[4*q+1] = u.y; wc[4*q+2] = u.z; wc[4*q+3] = u.w;
                }
                #pragma unroll
                for (int kw = 0; kw < 3; ++kw) {
                    const float w0 = w4[((0 * 4 + ci) * 3 + kh) * 3 + kw];
                    const float w1 = w4[((1 * 4 + ci) * 3 + kh) * 3 + kw];
                    #pragma unroll
                    for (int p = 0; p < 4; ++p) {
                        const int j = p + kw + 3;
                        den[0][p] = fmaf(w0, wc[j], den[0][p]);
                        nom[0][p] = fmaf(w0, wd[j], nom[0][p]);
                        den[1][p] = fmaf(w1, wc[j], den[1][p]);
                        nom[1][p] = fmaf(w1, wd[j], nom[1][p]);
                    }
                }
            }
        }
        conv_low<2>(&sx4_d[0][0][0], &sx4_c[0][0][0], w4, lh, lw, den, nom);

        float4 uo[2], co4[2];
        nconv_epilogue<4, 3>(w4, b4, den, nom, uo, co4);
        #pragma unroll
        for (int c = 0; c < 2; ++c) {
            const int a = ((b * 2 + c) << 12) + ((bh + lh) << 5) + ((bw + lw) >> 2);
            ((float4*)x34U)[a] = uo[c];
            ((float4*)x34C)[a] = co4[c];
        }
    }
}

// ---------------------------------------------------------------------------
// Decoder cat-nconv (3x3, skip @full + up2(low @half)); optional fused final
// 1x1 writing d_out.
// ---------------------------------------------------------------------------
template<bool UP_FIRST, int LOGHW, bool FINAL>
__global__ __launch_bounds__(256)
void nconv_cat_tiled(const float* __restrict__ skU, const float* __restrict__ skC,
                     const float* __restrict__ loU, const float* __restrict__ loC,
                     const float* __restrict__ wgt, const float* __restrict__ bias,
                     float* __restrict__ uout, float* __restrict__ cout,
                     const float* __restrict__ w7, const float* __restrict__ b7)
{
    constexpr int HW = 1 << LOGHW;
    constexpr int HWL = HW >> 1;
    constexpr int TH = 16;
    constexpr int ROWS = TH + 2;
    constexpr int NC4 = 18;
    constexpr int SK0 = UP_FIRST ? 2 : 0;
    constexpr int LO0 = UP_FIRST ? 0 : 2;
    __shared__ __align__(16) float s_d[2][ROWS][72];
    __shared__ __align__(16) float s_c[2][ROWS][72];
    __shared__ __align__(16) float s_lo_d[2][10][40];
    __shared__ __align__(16) float s_lo_c[2][10][40];

    const int tid = threadIdx.x;
    const int base_w = blockIdx.x * 64;
    const int base_h = blockIdx.y * TH;
    const int b = blockIdx.z;

    constexpr int SLOTS = 2 * ROWS * NC4;
    const float4* sU4 = (const float4*)skU;
    const float4* sC4 = (const float4*)skC;
    for (int i = tid; i < SLOTS; i += 256) {
        const int ci = i / (ROWS * NC4);
        const int r  = (i / NC4) % ROWS;
        const int cf = i % NC4;
        const int gh = base_h - 1 + r;
        const int gw4 = (base_w >> 2) + cf - 1;
        float4 dd = make_float4(0.f, 0.f, 0.f, 0.f);
        float4 cc = make_float4(0.f, 0.f, 0.f, 0.f);
        if ((unsigned)gh < (unsigned)HW && (unsigned)gw4 < (unsigned)(HW >> 2)) {
            const int a = ((b * 2 + ci) << (2 * LOGHW - 2)) + (gh << (LOGHW - 2)) + gw4;
            dd = sU4[a];
            cc = sC4[a];
        }
        *(float4*)&s_d[ci][r][cf * 4] = dd;
        *(float4*)&s_c[ci][r][cf * 4] = cc;
    }
    constexpr int LO_SLOTS = 2 * 10 * 10;
    const int lo_r0 = (base_h >> 1) - 1;
    const int lo_c4_0 = (base_w >> 3) - 1;
    const float4* lU4 = (const float4*)loU;
    const float4* lC4 = (const float4*)loC;
    for (int i = tid; i < LO_SLOTS; i += 256) {
        const int ci = i / 100;
        const int r  = (i / 10) % 10;
        const int cf = i % 10;
        const int gr = lo_r0 + r;
        const int gc4 = lo_c4_0 + cf;
        float4 dd = make_float4(0.f, 0.f, 0.f, 0.f);
        float4 cc = make_float4(0.f, 0.f, 0.f, 0.f);
        if ((unsigned)gr < (unsigned)HWL && (unsigned)gc4 < (unsigned)(HWL >> 2)) {
            const int a = ((b * 2 + ci) << (2 * (LOGHW - 1) - 2)) + (gr << (LOGHW - 3)) + gc4;
            dd = lU4[a];
            cc = lC4[a];
        }
        *(float4*)&s_lo_d[ci][r][cf * 4] = dd;
        *(float4*)&s_lo_c[ci][r][cf * 4] = cc;
    }
    __syncthreads();

    const int lh = tid >> 4;
    const int lw = (tid & 15) << 2;
    float den[2][4], nom[2][4];
    #pragma unroll
    for (int c = 0; c < 2; ++c)
        #pragma unroll
        for (int p = 0; p < 4; ++p) { den[c][p] = 0.f; nom[c][p] = 0.f; }

    conv_core<2, SK0, 4, 3, ROWS>(&s_d[0][0][0], &s_c[0][0][0], wgt, lh, lw, den, nom);
    conv_low<LO0>(&s_lo_d[0][0][0], &s_lo_c[0][0][0], wgt, lh, lw, den, nom);

    float4 uo[2], co4[2];
    nconv_epilogue<4, 3>(wgt, bias, den, nom, uo, co4);

    const int oh = base_h + lh;
    if (FINAL) {
        const float w70 = w7[0], w71 = w7[1], bb7 = b7[0];
        const float inv = frcp(w70 + w71);
        float4 xo4, cc4;
        #pragma unroll
        for (int p = 0; p < 4; ++p) {
            const float d1 = w70 * (&co4[0].x)[p] + w71 * (&co4[1].x)[p];
            (&xo4.x)[p] = (w70 * (&uo[0].x)[p] + w71 * (&uo[1].x)[p]) * frcp(d1 + EPSF) + bb7;
            (&cc4.x)[p] = d1 * inv;
        }
        const int a = (b << (2 * LOGHW - 2)) + (oh << (LOGHW - 2)) + ((base_w + lw) >> 2);
        ((float4*)uout)[a] = xo4;
        ((float4*)uout)[(1 << 19) + a] = cc4;
    } else {
        #pragma unroll
        for (int c = 0; c < 2; ++c) {
            const int a = ((b * 2 + c) << (2 * LOGHW - 2)) + (oh << (LOGHW - 2)) + ((base_w + lw) >> 2);
            ((float4*)uout)[a] = uo[c];
            ((float4*)cout)[a] = co4[c];
        }
    }
}

// ---------------------------------------------------------------------------
extern "C" void kernel_launch(void* const* d_in, const int* in_sizes, int n_in,
                              void* d_out, int out_size, void* d_ws, size_t ws_size,
                              hipStream_t stream) {
    (void)in_sizes; (void)n_in; (void)out_size; (void)ws_size;
    const float* x0 = (const float*)d_in[0];
    const float* c0 = (const float*)d_in[1];
    const float* w1 = (const float*)d_in[2];  const float* b1 = (const float*)d_in[3];
    const float* w2 = (const float*)d_in[4];  const float* b2 = (const float*)d_in[5];
    const float* w3 = (const float*)d_in[6];  const float* b3 = (const float*)d_in[7];
    const float* w4 = (const float*)d_in[8];  const float* b4 = (const float*)d_in[9];
    const float* w5 = (const float*)d_in[10]; const float* b5 = (const float*)d_in[11];
    const float* w6 = (const float*)d_in[12]; const float* b6 = (const float*)d_in[13];
    const float* w7 = (const float*)d_in[14]; const float* b7 = (const float*)d_in[15];

    float* ws = (float*)d_ws;
    const size_t S512 = 8ull * 2 * 512 * 512;
    const size_t S256 = 8ull * 2 * 256 * 256;
    const size_t S128 = 8ull * 2 * 128 * 128;

    float* X1x = ws;            float* X1c = ws + S512;
    float* E2x = ws + 2 * S512; float* E2c = ws + 3 * S512;
    float* off  = ws + 4 * S512;
    float* p1x  = off;               float* p1c  = off + S256;
    float* x2x  = off + 2 * S256;    float* x2c  = off + 3 * S256;
    float* x23x = off + 4 * S256;    float* x23c = off + 5 * S256;
    float* off2 = off + 6 * S256;
    float* p2x  = off2;              float* p2c  = off2 + S128;
    float* x34x = off2 + 2 * S128;   float* x34c = off2 + 3 * S128;

    // K1: enc stages 1+2 fused @512
    nconv2_tiled<1, 9, false, false><<<dim3(8, 32, 8), 256, 0, stream>>>(
        x0, c0, w1, b1, w2, b2, E2x, E2c, nullptr, nullptr);
    // K2: enc stage 3 @512 + pool -> X1 (skip), p1 @256
    nconv_tiled<2, 5, 9, true, true><<<dim3(8, 32, 8), 256, 0, stream>>>(
        E2x, E2c, w3, b3, X1x, X1c, p1x, p1c);
    // K3: enc stages 4+5 fused @256 + pool -> x2 @256, p2 @128
    nconv2_tiled<2, 8, true, true><<<dim3(4, 16, 8), 256, 0, stream>>>(
        p1x, p1c, w2, b2, w3, b3, x2x, x2c, p2x, p2c);
    // K4: whole @128/@64 sub-net -> x34 @128
    mid_kern<<<dim3(2, 8, 8), 256, 0, stream>>>(p2x, p2c, w2, b2, w4, b4, x34x, x34c);
    // K5: cat @256 -> x23
    nconv_cat_tiled<false, 8, false><<<dim3(4, 16, 8), 256, 0, stream>>>(
        x2x, x2c, x34x, x34c, w5, b5, x23x, x23c, nullptr, nullptr);
    // K6: cat @512 + final 1x1 -> d_out
    nconv_cat_tiled<true, 9, true><<<dim3(8, 32, 8), 256, 0, stream>>>(
        X1x, X1c, x23x, x23c, w6, b6, (float*)d_out, nullptr, w7, b7);
}